// Round 1
// baseline (249.109 us; speedup 1.0000x reference)
//
#include <hip/hip_runtime.h>

#define BB 8
#define NN 2048
#define FF 128

// ws layout (floats):
//   [0,128)            w_ai
//   [128, 1152)        xsum  (B*F)
//   [1152, 2176)       S     (B*F)
//   [2176, 18560)      p     (B*N)
//   [18560, 34944)     r     (B*N)

// K0: w_ai[c] = sum_f W[c,f] * a[F + f]   (a_i = second half of a)
__global__ __launch_bounds__(128) void k0_wai(const float* __restrict__ W,
                                              const float* __restrict__ a,
                                              float* __restrict__ w_ai) {
    int c = threadIdx.x;
    float s = 0.f;
#pragma unroll 8
    for (int f = 0; f < FF; ++f) s += W[c * FF + f] * a[FF + f];
    w_ai[c] = s;
}

// K1: p[b,n] = exp(X[b,n,:] . w_ai); xsum[b,c] += column sums of X
// grid: B * (N/64) blocks, 256 threads (4 waves), 64 rows/block (16 rows/wave)
__global__ __launch_bounds__(256) void k1_p_xsum(const float* __restrict__ X,
                                                 const float* __restrict__ w_ai,
                                                 float* __restrict__ p,
                                                 float* __restrict__ xsum) {
    int blk = blockIdx.x;
    int b = blk / (NN / 64);
    int row0 = (blk % (NN / 64)) * 64;
    int lane = threadIdx.x & 63;
    int wave = threadIdx.x >> 6;

    const float2* X2 = (const float2*)(X + ((size_t)b * NN + row0) * FF);
    float2 wv = ((const float2*)w_ai)[lane];
    float csx = 0.f, csy = 0.f;

    for (int it = 0; it < 16; ++it) {
        int rloc = wave * 16 + it;
        float2 xv = X2[(size_t)rloc * 64 + lane];
        csx += xv.x;
        csy += xv.y;
        float s = xv.x * wv.x + xv.y * wv.y;
#pragma unroll
        for (int off = 32; off; off >>= 1) s += __shfl_xor(s, off, 64);
        if (lane == 0) p[(size_t)b * NN + row0 + rloc] = expf(s);
    }

    __shared__ float cs_lds[4][FF];
    cs_lds[wave][lane * 2]     = csx;
    cs_lds[wave][lane * 2 + 1] = csy;
    __syncthreads();
    if (threadIdx.x < FF) {
        float v = cs_lds[0][threadIdx.x] + cs_lds[1][threadIdx.x] +
                  cs_lds[2][threadIdx.x] + cs_lds[3][threadIdx.x];
        atomicAdd(&xsum[b * FF + threadIdx.x], v);
    }
}

// K2: S[b,f] = sum_c xsum[b,c] * W[c,f]      grid 8, block 128
__global__ __launch_bounds__(128) void k2_S(const float* __restrict__ W,
                                            const float* __restrict__ xsum,
                                            float* __restrict__ S) {
    int b = blockIdx.x;
    int f = threadIdx.x;
    float s = 0.f;
#pragma unroll 8
    for (int c = 0; c < FF; ++c) s += xsum[b * FF + c] * W[c * FF + f];
    S[b * FF + f] = s;
}

// K3: r[b,i] = p[b,i] / (A[b,i,:] . p[b,:])   (0 if denom == 0)
// grid: B*N/4 blocks, 256 threads = 4 waves, one A-row per wave
__global__ __launch_bounds__(256) void k3_r(const float* __restrict__ A,
                                            const float* __restrict__ p,
                                            float* __restrict__ r) {
    __shared__ float p_lds[NN];
    int row0 = blockIdx.x * 4;       // global row in [0, B*N)
    int b = row0 >> 11;              // /NN

    const float4* p4 = (const float4*)(p + (size_t)b * NN);
    ((float4*)p_lds)[threadIdx.x]       = p4[threadIdx.x];
    ((float4*)p_lds)[threadIdx.x + 256] = p4[threadIdx.x + 256];
    __syncthreads();

    int lane = threadIdx.x & 63;
    int wave = threadIdx.x >> 6;
    int row = row0 + wave;
    const float4* A4 = (const float4*)(A + (size_t)row * NN);

    float acc = 0.f;
#pragma unroll
    for (int it = 0; it < 8; ++it) {
        float4 av = A4[it * 64 + lane];
        float4 pv = *(const float4*)&p_lds[it * 256 + lane * 4];
        acc += av.x * pv.x + av.y * pv.y + av.z * pv.z + av.w * pv.w;
    }
#pragma unroll
    for (int off = 32; off; off >>= 1) acc += __shfl_xor(acc, off, 64);

    if (lane == 0) {
        int i = row & (NN - 1);
        r[row] = (acc != 0.f) ? (p_lds[i] / acc) : 0.f;
    }
}

// K4: H[b,i,f] = (A[b,i,:] . r[b,:]) * S[b,f] + bias_W[f]
__global__ __launch_bounds__(256) void k4_H(const float* __restrict__ A,
                                            const float* __restrict__ rr,
                                            const float* __restrict__ S,
                                            const float* __restrict__ bias_W,
                                            float* __restrict__ Hout) {
    __shared__ float r_lds[NN];
    __shared__ float s_lds[FF];
    __shared__ float bw_lds[FF];
    int row0 = blockIdx.x * 4;
    int b = row0 >> 11;

    const float4* r4 = (const float4*)(rr + (size_t)b * NN);
    ((float4*)r_lds)[threadIdx.x]       = r4[threadIdx.x];
    ((float4*)r_lds)[threadIdx.x + 256] = r4[threadIdx.x + 256];
    if (threadIdx.x < FF) {
        s_lds[threadIdx.x]  = S[b * FF + threadIdx.x];
        bw_lds[threadIdx.x] = bias_W[threadIdx.x];
    }
    __syncthreads();

    int lane = threadIdx.x & 63;
    int wave = threadIdx.x >> 6;
    int row = row0 + wave;
    const float4* A4 = (const float4*)(A + (size_t)row * NN);

    float acc = 0.f;
#pragma unroll
    for (int it = 0; it < 8; ++it) {
        float4 av = A4[it * 64 + lane];
        float4 rv = *(const float4*)&r_lds[it * 256 + lane * 4];
        acc += av.x * rv.x + av.y * rv.y + av.z * rv.z + av.w * rv.w;
    }
#pragma unroll
    for (int off = 32; off; off >>= 1) acc += __shfl_xor(acc, off, 64);
    // every lane now holds t = acc

    float2 sv = ((const float2*)s_lds)[lane];
    float2 bv = ((const float2*)bw_lds)[lane];
    float2 hv;
    hv.x = acc * sv.x + bv.x;
    hv.y = acc * sv.y + bv.y;
    ((float2*)Hout)[(size_t)row * 64 + lane] = hv;
}

extern "C" void kernel_launch(void* const* d_in, const int* in_sizes, int n_in,
                              void* d_out, int out_size, void* d_ws, size_t ws_size,
                              hipStream_t stream) {
    const float* X      = (const float*)d_in[0];
    const float* A      = (const float*)d_in[1];
    const float* W      = (const float*)d_in[2];
    const float* a      = (const float*)d_in[3];
    // d_in[4] = bias_a : algebraically cancels (rank-1 den), unused
    const float* bias_W = (const float*)d_in[5];
    float* out = (float*)d_out;

    float* ws   = (float*)d_ws;
    float* w_ai = ws;            // 128
    float* xsum = ws + 128;      // 1024
    float* S    = ws + 1152;     // 1024
    float* p    = ws + 2176;     // 16384
    float* r    = ws + 18560;    // 16384

    hipMemsetAsync(xsum, 0, BB * FF * sizeof(float), stream);

    k0_wai<<<1, 128, 0, stream>>>(W, a, w_ai);
    k1_p_xsum<<<BB * (NN / 64), 256, 0, stream>>>(X, w_ai, p, xsum);
    k2_S<<<BB, 128, 0, stream>>>(W, xsum, S);
    k3_r<<<(BB * NN) / 4, 256, 0, stream>>>(A, p, r);
    k4_H<<<(BB * NN) / 4, 256, 0, stream>>>(A, r, S, bias_W, out);
}

// Round 3
// 240.717 us; speedup vs baseline: 1.0349x; 1.0349x over previous
//
#include <hip/hip_runtime.h>

#define BB 8
#define NN 2048
#define FF 128

// ws layout (floats):
//   [0,128)            w_ai
//   [128, 1152)        xsum  (B*F)
//   [1152, 2176)       S     (B*F)
//   [2176, 18560)      p     (B*N)
//   [18560, 34944)     r     (B*N)
//   [34944, ...)       packed A bits (u64[B*N*32] = 4 MB), 8B-aligned

// K0: w_ai[c] = sum_f W[c,f] * a[F + f]   (a_i = second half of a)
__global__ __launch_bounds__(128) void k0_wai(const float* __restrict__ W,
                                              const float* __restrict__ a,
                                              float* __restrict__ w_ai) {
    int c = threadIdx.x;
    float s = 0.f;
#pragma unroll 8
    for (int f = 0; f < FF; ++f) s += W[c * FF + f] * a[FF + f];
    w_ai[c] = s;
}

// K1: p[b,n] = exp(X[b,n,:] . w_ai); xsum[b,:] += column sums of X
// grid 512 blocks x 256 thr; 32 rows/block; half-wave (32 lanes) per row.
__global__ __launch_bounds__(256) void k1_p_xsum(const float* __restrict__ X,
                                                 const float* __restrict__ w_ai,
                                                 float* __restrict__ p,
                                                 float* __restrict__ xsum) {
    __shared__ float xls[FF];
    int gr0 = blockIdx.x * 32;          // global row in [0, B*N), 32 | 2048
    int b = gr0 >> 11;
    int lane = threadIdx.x & 63;
    int wave = threadIdx.x >> 6;
    int half = lane >> 5;
    int l32 = lane & 31;

    if (threadIdx.x < FF) xls[threadIdx.x] = 0.f;
    __syncthreads();

    float4 wv = ((const float4*)w_ai)[l32];
    float4 cs = make_float4(0.f, 0.f, 0.f, 0.f);
    const float4* X4 = (const float4*)(X + (size_t)gr0 * FF);

#pragma unroll
    for (int it = 0; it < 4; ++it) {
        int rloc = wave * 8 + it * 2 + half;
        float4 xv = X4[(size_t)rloc * 32 + l32];
        cs.x += xv.x; cs.y += xv.y; cs.z += xv.z; cs.w += xv.w;
        float s = xv.x * wv.x + xv.y * wv.y + xv.z * wv.z + xv.w * wv.w;
#pragma unroll
        for (int off = 16; off; off >>= 1) s += __shfl_xor(s, off, 64);
        if (l32 == 0) p[(size_t)gr0 + rloc] = expf(s);
    }

    atomicAdd(&xls[l32 * 4 + 0], cs.x);
    atomicAdd(&xls[l32 * 4 + 1], cs.y);
    atomicAdd(&xls[l32 * 4 + 2], cs.z);
    atomicAdd(&xls[l32 * 4 + 3], cs.w);
    __syncthreads();
    if (threadIdx.x < FF) atomicAdd(&xsum[b * FF + threadIdx.x], xls[threadIdx.x]);
}

// K2: S[b,f] = sum_c xsum[b,c] * W[c,f]      grid 8, block 128
__global__ __launch_bounds__(128) void k2_S(const float* __restrict__ W,
                                            const float* __restrict__ xsum,
                                            float* __restrict__ S) {
    int b = blockIdx.x;
    int f = threadIdx.x;
    float s = 0.f;
#pragma unroll 8
    for (int c = 0; c < FF; ++c) s += xsum[b * FF + c] * W[c * FF + f];
    S[b * FF + f] = s;
}

// K3: r[b,i] = p[b,i] / (A[b,i,:] . p[b,:])   (0 if denom == 0)
// Also emits a bit-packed copy of A: pk[row*32 + it*4 + c] (u64), where
// bit l of word (it*4+c) = (A[row][it*256 + 4*l + c] != 0).
// grid 2048 blocks x 256 thr = 4 waves; 2 rows per wave; p staged in LDS.
__global__ __launch_bounds__(256) void k3_r(const float* __restrict__ A,
                                            const float* __restrict__ p,
                                            float* __restrict__ r,
                                            unsigned long long* __restrict__ pk) {
    __shared__ float p_lds[NN];
    int row0 = blockIdx.x * 8;
    int b = row0 >> 11;

    const float4* p4 = (const float4*)(p + (size_t)b * NN);
    float4* pl4 = (float4*)p_lds;
    pl4[threadIdx.x]       = p4[threadIdx.x];
    pl4[threadIdx.x + 256] = p4[threadIdx.x + 256];
    __syncthreads();

    int lane = threadIdx.x & 63;
    int wave = threadIdx.x >> 6;
    int rowA = row0 + wave * 2;
    int rowB = rowA + 1;
    const float4* Aa = (const float4*)(A + (size_t)rowA * NN);
    const float4* Ab = (const float4*)(A + (size_t)rowB * NN);

    int c = lane & 3;
    float accA = 0.f, accB = 0.f;
#pragma unroll
    for (int it = 0; it < 8; ++it) {
        float4 pv = pl4[it * 64 + lane];
        float4 va = Aa[it * 64 + lane];
        float4 vb = Ab[it * 64 + lane];
        accA += va.x * pv.x + va.y * pv.y + va.z * pv.z + va.w * pv.w;
        accB += vb.x * pv.x + vb.y * pv.y + vb.z * pv.z + vb.w * pv.w;

        unsigned long long a0 = __ballot(va.x != 0.f);
        unsigned long long a1 = __ballot(va.y != 0.f);
        unsigned long long a2 = __ballot(va.z != 0.f);
        unsigned long long a3 = __ballot(va.w != 0.f);
        unsigned long long b0 = __ballot(vb.x != 0.f);
        unsigned long long b1 = __ballot(vb.y != 0.f);
        unsigned long long b2 = __ballot(vb.z != 0.f);
        unsigned long long b3 = __ballot(vb.w != 0.f);
        if (lane < 8) {
            // static selection by lane bits (no runtime-indexed arrays)
            unsigned long long alo = (c & 1) ? a1 : a0;
            unsigned long long ahi = (c & 1) ? a3 : a2;
            unsigned long long am  = (c & 2) ? ahi : alo;
            unsigned long long blo = (c & 1) ? b1 : b0;
            unsigned long long bhi = (c & 1) ? b3 : b2;
            unsigned long long bm  = (c & 2) ? bhi : blo;
            int row = (lane < 4) ? rowA : rowB;
            unsigned long long m = (lane < 4) ? am : bm;
            pk[(size_t)row * 32 + it * 4 + c] = m;
        }
    }
#pragma unroll
    for (int off = 32; off; off >>= 1) {
        accA += __shfl_xor(accA, off, 64);
        accB += __shfl_xor(accB, off, 64);
    }

    if (lane == 0) {
        r[rowA] = (accA != 0.f) ? (p_lds[rowA & (NN - 1)] / accA) : 0.f;
        r[rowB] = (accB != 0.f) ? (p_lds[rowB & (NN - 1)] / accB) : 0.f;
    }
}

// K4: H[b,i,f] = (A[b,i,:] . r[b,:]) * S[b,f] + bias_W[f]
// Reads bit-packed A (4 MB, cache-resident) instead of float A (134 MB).
// grid 2048 blocks x 256 thr; 2 rows per wave; r staged in LDS.
__global__ __launch_bounds__(256) void k4_H(const unsigned long long* __restrict__ pk,
                                            const float* __restrict__ rr,
                                            const float* __restrict__ S,
                                            const float* __restrict__ bias_W,
                                            float* __restrict__ Hout) {
    __shared__ float r_lds[NN];
    __shared__ float s_lds[FF];
    __shared__ float bw_lds[FF];
    int row0 = blockIdx.x * 8;
    int b = row0 >> 11;

    const float4* r4 = (const float4*)(rr + (size_t)b * NN);
    float4* rl4 = (float4*)r_lds;
    rl4[threadIdx.x]       = r4[threadIdx.x];
    rl4[threadIdx.x + 256] = r4[threadIdx.x + 256];
    if (threadIdx.x < FF) {
        s_lds[threadIdx.x]  = S[b * FF + threadIdx.x];
        bw_lds[threadIdx.x] = bias_W[threadIdx.x];
    }
    __syncthreads();

    int lane = threadIdx.x & 63;
    int wave = threadIdx.x >> 6;
    int rowA = row0 + wave * 2;
    int rowB = rowA + 1;

    // lanes 0..31 hold rowA's 32 mask words; lanes 32..63 hold rowB's.
    unsigned long long w =
        pk[(size_t)(lane < 32 ? rowA : rowB) * 32 + (lane & 31)];

    float accA = 0.f, accB = 0.f;
#pragma unroll
    for (int it = 0; it < 8; ++it) {
        float4 rv = rl4[it * 64 + lane];
        unsigned long long mA0 = __shfl(w, it * 4 + 0, 64);
        unsigned long long mA1 = __shfl(w, it * 4 + 1, 64);
        unsigned long long mA2 = __shfl(w, it * 4 + 2, 64);
        unsigned long long mA3 = __shfl(w, it * 4 + 3, 64);
        unsigned long long mB0 = __shfl(w, 32 + it * 4 + 0, 64);
        unsigned long long mB1 = __shfl(w, 32 + it * 4 + 1, 64);
        unsigned long long mB2 = __shfl(w, 32 + it * 4 + 2, 64);
        unsigned long long mB3 = __shfl(w, 32 + it * 4 + 3, 64);
        if ((mA0 >> lane) & 1ull) accA += rv.x;
        if ((mA1 >> lane) & 1ull) accA += rv.y;
        if ((mA2 >> lane) & 1ull) accA += rv.z;
        if ((mA3 >> lane) & 1ull) accA += rv.w;
        if ((mB0 >> lane) & 1ull) accB += rv.x;
        if ((mB1 >> lane) & 1ull) accB += rv.y;
        if ((mB2 >> lane) & 1ull) accB += rv.z;
        if ((mB3 >> lane) & 1ull) accB += rv.w;
    }
#pragma unroll
    for (int off = 32; off; off >>= 1) {
        accA += __shfl_xor(accA, off, 64);
        accB += __shfl_xor(accB, off, 64);
    }
    // every lane holds accA/accB

    float2 sv = ((const float2*)s_lds)[lane];
    float2 bv = ((const float2*)bw_lds)[lane];
    float2* H2 = (float2*)Hout;
    float2 ha, hb;
    ha.x = accA * sv.x + bv.x;  ha.y = accA * sv.y + bv.y;
    hb.x = accB * sv.x + bv.x;  hb.y = accB * sv.y + bv.y;
    H2[(size_t)rowA * 64 + lane] = ha;
    H2[(size_t)rowB * 64 + lane] = hb;
}

extern "C" void kernel_launch(void* const* d_in, const int* in_sizes, int n_in,
                              void* d_out, int out_size, void* d_ws, size_t ws_size,
                              hipStream_t stream) {
    const float* X      = (const float*)d_in[0];
    const float* A      = (const float*)d_in[1];
    const float* W      = (const float*)d_in[2];
    const float* a      = (const float*)d_in[3];
    // d_in[4] = bias_a : algebraically cancels (rank-1 den), unused
    const float* bias_W = (const float*)d_in[5];
    float* out = (float*)d_out;

    float* ws   = (float*)d_ws;
    float* w_ai = ws;            // 128
    float* xsum = ws + 128;      // 1024
    float* S    = ws + 1152;     // 1024
    float* p    = ws + 2176;     // 16384
    float* r    = ws + 18560;    // 16384
    unsigned long long* pk = (unsigned long long*)(ws + 34944);  // 8B-aligned

    hipMemsetAsync(xsum, 0, BB * FF * sizeof(float), stream);

    k0_wai<<<1, 128, 0, stream>>>(W, a, w_ai);
    k1_p_xsum<<<(BB * NN) / 32, 256, 0, stream>>>(X, w_ai, p, xsum);
    k2_S<<<BB, 128, 0, stream>>>(W, xsum, S);
    k3_r<<<(BB * NN) / 8, 256, 0, stream>>>(A, p, r, pk);
    k4_H<<<(BB * NN) / 8, 256, 0, stream>>>(pk, r, S, bias_W, out);
}

// Round 4
// 236.195 us; speedup vs baseline: 1.0547x; 1.0191x over previous
//
#include <hip/hip_runtime.h>

#define BB 8
#define NN 2048
#define FF 128

// ws layout (floats):
//   [0, 65536)         xpart  (512 blocks x 128 per-block column sums of X)
//   [65536, 66560)     S      (B*F)
//   [66560, 82944)     p      (B*N)
//   [82944, 99328)     r      (B*N)
//   [99328, ...)       pk     (u64[B*N*32] = 4 MB, byte offset 397312, 8B-aligned)

// K1: p[b,n] = exp(X[b,n,:] . w_ai); xpart[blk,:] = column sums of X slice.
// w_ai = W . a_i computed redundantly per block into LDS (W is L2-resident).
// grid 512 blocks x 256 thr; 32 rows/block; half-wave (32 lanes) per row.
__global__ __launch_bounds__(256) void k1_p_xsum(const float* __restrict__ X,
                                                 const float* __restrict__ W,
                                                 const float* __restrict__ a,
                                                 float* __restrict__ p,
                                                 float* __restrict__ xpart) {
    __shared__ float wls[FF];
    __shared__ float xls[FF];
    int t = threadIdx.x;
    if (t < FF) {
        float s = 0.f;
#pragma unroll 8
        for (int f = 0; f < FF; ++f) s += W[t * FF + f] * a[FF + f];
        wls[t] = s;
        xls[t] = 0.f;
    }
    __syncthreads();

    int gr0 = blockIdx.x * 32;          // global row in [0, B*N)
    int lane = t & 63;
    int wave = t >> 6;
    int half = lane >> 5;
    int l32 = lane & 31;

    float4 wv = ((const float4*)wls)[l32];
    float4 cs = make_float4(0.f, 0.f, 0.f, 0.f);
    const float4* X4 = (const float4*)(X + (size_t)gr0 * FF);

#pragma unroll
    for (int it = 0; it < 4; ++it) {
        int rloc = wave * 8 + it * 2 + half;
        float4 xv = X4[(size_t)rloc * 32 + l32];
        cs.x += xv.x; cs.y += xv.y; cs.z += xv.z; cs.w += xv.w;
        float s = xv.x * wv.x + xv.y * wv.y + xv.z * wv.z + xv.w * wv.w;
#pragma unroll
        for (int off = 16; off; off >>= 1) s += __shfl_xor(s, off, 64);
        if (l32 == 0) p[(size_t)gr0 + rloc] = expf(s);
    }

    atomicAdd(&xls[l32 * 4 + 0], cs.x);
    atomicAdd(&xls[l32 * 4 + 1], cs.y);
    atomicAdd(&xls[l32 * 4 + 2], cs.z);
    atomicAdd(&xls[l32 * 4 + 3], cs.w);
    __syncthreads();
    if (t < FF) xpart[blockIdx.x * FF + t] = xls[t];
}

// K3: block 0: xsum = reduce(xpart); S[b,:] = xsum[b,:] . W   (runs alongside)
//     blocks 1..2048: r[b,i] = p[b,i] / (A[b,i,:] . p[b,:])  (0 if denom==0)
//     + emits bit-packed A: bit l of pk[row*32+it*4+c] = A[row][it*256+4l+c]!=0
// grid 2049 blocks x 256 thr; 2 rows per wave; p staged in LDS.
__global__ __launch_bounds__(256) void k3_r(const float* __restrict__ A,
                                            const float* __restrict__ W,
                                            const float* __restrict__ xpart,
                                            const float* __restrict__ p,
                                            float* __restrict__ r,
                                            float* __restrict__ S,
                                            unsigned long long* __restrict__ pk) {
    __shared__ float p_lds[NN];
    int t = threadIdx.x;

    if (blockIdx.x == 0) {
        // stage 1: xsum[b,f] = sum of 64 per-block partials (into p_lds[0..1024))
#pragma unroll
        for (int k = 0; k < 4; ++k) {
            int o = t + 256 * k;            // (b,f), o in [0,1024)
            int b = o >> 7, f = o & 127;
            float s = 0.f;
            for (int j = 0; j < 64; ++j) s += xpart[(b * 64 + j) * FF + f];
            p_lds[o] = s;
        }
        __syncthreads();
        // stage 2: S[b,f] = sum_c xsum[b,c] * W[c,f]
#pragma unroll
        for (int k = 0; k < 4; ++k) {
            int o = t + 256 * k;
            int b = o >> 7, f = o & 127;
            float s = 0.f;
#pragma unroll 8
            for (int c = 0; c < FF; ++c) s += p_lds[b * FF + c] * W[c * FF + f];
            S[o] = s;
        }
        return;
    }

    int row0 = (blockIdx.x - 1) * 8;
    int b = row0 >> 11;

    const float4* p4 = (const float4*)(p + (size_t)b * NN);
    float4* pl4 = (float4*)p_lds;
    pl4[t]       = p4[t];
    pl4[t + 256] = p4[t + 256];
    __syncthreads();

    int lane = t & 63;
    int wave = t >> 6;
    int rowA = row0 + wave * 2;
    int rowB = rowA + 1;
    const float4* Aa = (const float4*)(A + (size_t)rowA * NN);
    const float4* Ab = (const float4*)(A + (size_t)rowB * NN);

    int c = lane & 3;
    float accA = 0.f, accB = 0.f;
#pragma unroll
    for (int it = 0; it < 8; ++it) {
        float4 pv = pl4[it * 64 + lane];
        float4 va = Aa[it * 64 + lane];
        float4 vb = Ab[it * 64 + lane];
        accA += va.x * pv.x + va.y * pv.y + va.z * pv.z + va.w * pv.w;
        accB += vb.x * pv.x + vb.y * pv.y + vb.z * pv.z + vb.w * pv.w;

        unsigned long long a0 = __ballot(va.x != 0.f);
        unsigned long long a1 = __ballot(va.y != 0.f);
        unsigned long long a2 = __ballot(va.z != 0.f);
        unsigned long long a3 = __ballot(va.w != 0.f);
        unsigned long long b0 = __ballot(vb.x != 0.f);
        unsigned long long b1 = __ballot(vb.y != 0.f);
        unsigned long long b2 = __ballot(vb.z != 0.f);
        unsigned long long b3 = __ballot(vb.w != 0.f);
        if (lane < 8) {
            unsigned long long alo = (c & 1) ? a1 : a0;
            unsigned long long ahi = (c & 1) ? a3 : a2;
            unsigned long long am  = (c & 2) ? ahi : alo;
            unsigned long long blo = (c & 1) ? b1 : b0;
            unsigned long long bhi = (c & 1) ? b3 : b2;
            unsigned long long bm  = (c & 2) ? bhi : blo;
            int row = (lane < 4) ? rowA : rowB;
            unsigned long long m = (lane < 4) ? am : bm;
            pk[(size_t)row * 32 + it * 4 + c] = m;
        }
    }
#pragma unroll
    for (int off = 32; off; off >>= 1) {
        accA += __shfl_xor(accA, off, 64);
        accB += __shfl_xor(accB, off, 64);
    }

    if (lane == 0) {
        r[rowA] = (accA != 0.f) ? (p_lds[rowA & (NN - 1)] / accA) : 0.f;
        r[rowB] = (accB != 0.f) ? (p_lds[rowB & (NN - 1)] / accB) : 0.f;
    }
}

// K4: H[b,i,f] = (A[b,i,:] . r[b,:]) * S[b,f] + bias_W[f]
// Reads bit-packed A (4 MB, cache-resident) instead of float A (134 MB).
// grid 2048 blocks x 256 thr; 2 rows per wave; r staged in LDS.
__global__ __launch_bounds__(256) void k4_H(const unsigned long long* __restrict__ pk,
                                            const float* __restrict__ rr,
                                            const float* __restrict__ S,
                                            const float* __restrict__ bias_W,
                                            float* __restrict__ Hout) {
    __shared__ float r_lds[NN];
    __shared__ float s_lds[FF];
    __shared__ float bw_lds[FF];
    int row0 = blockIdx.x * 8;
    int b = row0 >> 11;

    const float4* r4 = (const float4*)(rr + (size_t)b * NN);
    float4* rl4 = (float4*)r_lds;
    rl4[threadIdx.x]       = r4[threadIdx.x];
    rl4[threadIdx.x + 256] = r4[threadIdx.x + 256];
    if (threadIdx.x < FF) {
        s_lds[threadIdx.x]  = S[b * FF + threadIdx.x];
        bw_lds[threadIdx.x] = bias_W[threadIdx.x];
    }
    __syncthreads();

    int lane = threadIdx.x & 63;
    int wave = threadIdx.x >> 6;
    int rowA = row0 + wave * 2;
    int rowB = rowA + 1;

    // lanes 0..31 hold rowA's 32 mask words; lanes 32..63 hold rowB's.
    unsigned long long w =
        pk[(size_t)(lane < 32 ? rowA : rowB) * 32 + (lane & 31)];

    float accA = 0.f, accB = 0.f;
#pragma unroll
    for (int it = 0; it < 8; ++it) {
        float4 rv = rl4[it * 64 + lane];
        unsigned long long mA0 = __shfl(w, it * 4 + 0, 64);
        unsigned long long mA1 = __shfl(w, it * 4 + 1, 64);
        unsigned long long mA2 = __shfl(w, it * 4 + 2, 64);
        unsigned long long mA3 = __shfl(w, it * 4 + 3, 64);
        unsigned long long mB0 = __shfl(w, 32 + it * 4 + 0, 64);
        unsigned long long mB1 = __shfl(w, 32 + it * 4 + 1, 64);
        unsigned long long mB2 = __shfl(w, 32 + it * 4 + 2, 64);
        unsigned long long mB3 = __shfl(w, 32 + it * 4 + 3, 64);
        if ((mA0 >> lane) & 1ull) accA += rv.x;
        if ((mA1 >> lane) & 1ull) accA += rv.y;
        if ((mA2 >> lane) & 1ull) accA += rv.z;
        if ((mA3 >> lane) & 1ull) accA += rv.w;
        if ((mB0 >> lane) & 1ull) accB += rv.x;
        if ((mB1 >> lane) & 1ull) accB += rv.y;
        if ((mB2 >> lane) & 1ull) accB += rv.z;
        if ((mB3 >> lane) & 1ull) accB += rv.w;
    }
#pragma unroll
    for (int off = 32; off; off >>= 1) {
        accA += __shfl_xor(accA, off, 64);
        accB += __shfl_xor(accB, off, 64);
    }
    // every lane holds accA/accB

    float2 sv = ((const float2*)s_lds)[lane];
    float2 bv = ((const float2*)bw_lds)[lane];
    float2* H2 = (float2*)Hout;
    float2 ha, hb;
    ha.x = accA * sv.x + bv.x;  ha.y = accA * sv.y + bv.y;
    hb.x = accB * sv.x + bv.x;  hb.y = accB * sv.y + bv.y;
    H2[(size_t)rowA * 64 + lane] = ha;
    H2[(size_t)rowB * 64 + lane] = hb;
}

extern "C" void kernel_launch(void* const* d_in, const int* in_sizes, int n_in,
                              void* d_out, int out_size, void* d_ws, size_t ws_size,
                              hipStream_t stream) {
    const float* X      = (const float*)d_in[0];
    const float* A      = (const float*)d_in[1];
    const float* W      = (const float*)d_in[2];
    const float* a      = (const float*)d_in[3];
    // d_in[4] = bias_a : algebraically cancels (rank-1 den), unused
    const float* bias_W = (const float*)d_in[5];
    float* out = (float*)d_out;

    float* ws    = (float*)d_ws;
    float* xpart = ws;            // 512*128 = 65536
    float* S     = ws + 65536;    // 1024
    float* p     = ws + 66560;    // 16384
    float* r     = ws + 82944;    // 16384
    unsigned long long* pk = (unsigned long long*)(ws + 99328);  // 4 MB

    k1_p_xsum<<<(BB * NN) / 32, 256, 0, stream>>>(X, W, a, p, xpart);
    k3_r<<<(BB * NN) / 8 + 1, 256, 0, stream>>>(A, W, xpart, p, r, S, pk);
    k4_H<<<(BB * NN) / 8, 256, 0, stream>>>(pk, r, S, bias_W, out);
}